// Round 3
// baseline (56.053 us; speedup 1.0000x reference)
//
#include <hip/hip_runtime.h>
#include <math.h>

#define DD 512
#define KC 32
#define NQ 524288
#define EPSF 1e-8f
#define CONE_STRIDE 13   // padded from 12 -> conflict-free LDS reads in k_sdf

// Scratch lives in the FRONT of d_out (16.7M floats): every region is fully
// written by stage n and consumed by stage n+1 BEFORE k_sdf overwrites it
// (stream order). Only `cones` (read DURING k_sdf) + the counter live in ws.
//   partialT : out[0      .. 262144)   [d 0..512)[b 0..512)
//   decPart  : out[262144 .. 327680)   [b 0..128)[d 0..512)
//   mapPart  : out[327680 .. 344064)   [b 0..64)[j 0..256)
#define OFF_PART 0
#define OFF_DECP 262144
#define OFF_MAPP 327680

__device__ __constant__ float c_mult[8]  = {1.f, 1.f, 1.f, 0.01f, 0.03f, 1.7f, 1.7f, 1.7f};
__device__ __constant__ float c_adder[8] = {-0.8f, -0.8f, -0.8f, 0.05f, 0.1f, -1.f, -1.f, -1.f};

// Stage 1: partialT[d][b] = sum over block b's 64 rows of vox[v]*W_enc[v][d].
// 512 blocks x 512 threads, coalesced float4 reads of W_enc (1KB/wave).
// Scatter store (4B @ 2KB stride) is absorbed by L2 (1MB total, fire&forget).
// Block 0 thread 0 also zeroes the k_map completion counter.
__global__ __launch_bounds__(512) void k_enc(const float* __restrict__ vox,
                                             const float* __restrict__ Wenc,
                                             float* __restrict__ partialT,
                                             unsigned int* __restrict__ cnt) {
    __shared__ float4 red4[512];
    const int t = threadIdx.x;
    const int b = blockIdx.x;
    if (b == 0 && t == 0) *cnt = 0u;
    const int g  = t >> 7;          // row group 0..3
    const int c4 = (t & 127) << 2;  // starting column
    const int v0 = b * 64;
    float4 acc = make_float4(0.f, 0.f, 0.f, 0.f);
    #pragma unroll
    for (int it = 0; it < 16; ++it) {
        const int v = v0 + it * 4 + g;
        const float sv = vox[v];
        const float4 w = *reinterpret_cast<const float4*>(&Wenc[(size_t)v * DD + c4]);
        acc.x += sv * w.x; acc.y += sv * w.y; acc.z += sv * w.z; acc.w += sv * w.w;
    }
    red4[t] = acc;
    __syncthreads();
    const float* red = reinterpret_cast<const float*>(red4);
    const float s = red[t] + red[512 + t] + red[1024 + t] + red[1536 + t];
    partialT[(size_t)t * 512 + b] = s;
}

// Stage 2: decPart[b][d] = sum_{i in block} relu(feat[i]+b_enc[i]) * W_dec[i][d]
// 128 blocks x 512 threads (4 rows/block). featsum row reduced from partialT
// (coalesced float4 + wave shuffle). Coalesced 2KB partial store. No atomics.
__global__ __launch_bounds__(512) void k_dec(const float* __restrict__ partialT,
                                             const float* __restrict__ benc,
                                             const float* __restrict__ Wdec,
                                             float* __restrict__ decPart) {
    __shared__ float4 red4[512];
    __shared__ float wsum[8];
    const int t = threadIdx.x;
    const int g = t >> 7;       // row group 0..3
    const int j = t & 127;
    const int i = blockIdx.x * 4 + g;
    const float4 pv = *reinterpret_cast<const float4*>(&partialT[(size_t)i * 512 + j * 4]);
    float s = pv.x + pv.y + pv.z + pv.w;
    #pragma unroll
    for (int off = 32; off >= 1; off >>= 1) s += __shfl_xor(s, off, 64);
    if ((t & 63) == 0) wsum[t >> 6] = s;
    __syncthreads();
    float fi = wsum[2 * g] + wsum[2 * g + 1] + benc[i];
    fi = fi > 0.f ? fi : 0.f;
    const float4 w = *reinterpret_cast<const float4*>(&Wdec[(size_t)i * DD + (j << 2)]);
    red4[t] = make_float4(fi * w.x, fi * w.y, fi * w.z, fi * w.w);
    __syncthreads();
    const float* red = reinterpret_cast<const float*>(red4);
    const float s2 = red[t] + red[512 + t] + red[1024 + t] + red[1536 + t];
    decPart[(size_t)blockIdx.x * 512 + t] = s2;   // coalesced
}

// Stage 3: 64 blocks x 512 threads. Block b owns rows i = 8b..8b+7:
//   dec[i] = relu(sum_p decPart[p][i] + b_dec[i])   (one wave per row)
//   mapPart[b][j] = sum_{r} dec[8b+r] * W_map[8b+r][j]
// Last-finished block (counter) reduces mapPart, applies sigmoid*mult+adder,
// writes the 256 output params AND the derived cone table. Wait-free.
__global__ __launch_bounds__(512) void k_map(const float* __restrict__ decPart,
                                             const float* __restrict__ bdec,
                                             const float* __restrict__ Wmap,
                                             float* __restrict__ mapPart,
                                             const float* __restrict__ bmap,
                                             float* __restrict__ out_params,
                                             float* __restrict__ cones,
                                             unsigned int* __restrict__ cnt) {
    __shared__ float dec8[8];
    __shared__ float half0[256];
    __shared__ float pbuf[256];
    __shared__ int lastflag;
    const int t = threadIdx.x;
    const int b = blockIdx.x;
    // --- reduce decPart columns for my 8 rows (wave w -> row i=8b+w) ---
    const int w = t >> 6, l = t & 63;
    const int i = b * 8 + w;
    float s = decPart[(size_t)(2 * l) * 512 + i] + decPart[(size_t)(2 * l + 1) * 512 + i];
    #pragma unroll
    for (int off = 32; off >= 1; off >>= 1) s += __shfl_xor(s, off, 64);
    if (l == 0) {
        const float d = s + bdec[i];
        dec8[w] = d > 0.f ? d : 0.f;
    }
    __syncthreads();
    // --- map: j = t&255, halves over rows ---
    const int j = t & 255, h = t >> 8;
    float acc = 0.f;
    #pragma unroll
    for (int r = 0; r < 4; ++r) {
        const int row = h * 4 + r;
        acc += dec8[row] * Wmap[(size_t)(b * 8 + row) * 256 + j];
    }
    if (h == 0) half0[j] = acc;
    __syncthreads();
    if (h == 1) mapPart[(size_t)b * 256 + j] = half0[j] + acc;   // coalesced
    __threadfence();
    __syncthreads();
    if (t == 0) lastflag = (atomicAdd(cnt, 1u) == 63u) ? 1 : 0;
    __syncthreads();
    if (!lastflag) return;
    __threadfence();
    // --- last block: reduce mapPart (64KB, L2-hot, coalesced) + params ---
    float m = 0.f;
    #pragma unroll 8
    for (int p = h * 32; p < h * 32 + 32; ++p) m += mapPart[(size_t)p * 256 + j];
    if (h == 0) half0[j] = m;
    __syncthreads();
    if (h == 1) {
        const float tot = half0[j] + m + bmap[j];
        const float sig = 1.f / (1.f + expf(-tot));
        const float val = sig * c_mult[j & 7] + c_adder[j & 7];
        out_params[j] = val;
        pbuf[j] = val;
    }
    __syncthreads();
    if (t < KC) {
        const float cx = pbuf[t*8+0], cy = pbuf[t*8+1], cz = pbuf[t*8+2];
        const float r  = pbuf[t*8+3], hh = pbuf[t*8+4];
        const float ox = pbuf[t*8+5], oy = pbuf[t*8+6], oz = pbuf[t*8+7];
        const float nrm = sqrtf(ox*ox + oy*oy + oz*oz) + EPSF;
        const float inv = 1.f / nrm;
        const float inv_h = 1.f / (hh + EPSF);
        float* ck = &cones[t * CONE_STRIDE];
        ck[0] = cx;       ck[1] = cy;      ck[2] = cz;
        ck[3] = ox * inv; ck[4] = oy * inv; ck[5] = oz * inv;
        ck[6] = r;        ck[7] = hh;      ck[8] = inv_h;
        ck[9] = r * inv_h; ck[10] = 0.f;   ck[11] = 0.f;  ck[12] = 0.f;
    }
}

// Stage 4: SDF eval, fully coalesced 1KB/wave writes.
// Block = 256 threads / 32 queries; thread t: query t>>3, cones (t&7)*4..+3.
__global__ __launch_bounds__(256) void k_sdf(const float* __restrict__ q,
                                             const float* __restrict__ cones,
                                             float* __restrict__ out) {
    __shared__ float sq[96];                 // 32 queries x 3
    __shared__ float c[KC * CONE_STRIDE];    // 416 floats
    const int t = threadIdx.x;
    const size_t n0 = (size_t)blockIdx.x * 32;
    if (t < 96) sq[t] = q[n0 * 3 + t];
    c[t] = cones[t];
    if (t < KC * CONE_STRIDE - 256) c[256 + t] = cones[256 + t];
    __syncthreads();
    const int nl = t >> 3;
    const int k0 = (t & 7) << 2;
    const float qx = sq[nl*3+0], qy = sq[nl*3+1], qz = sq[nl*3+2];
    float4 o;
    float* of = &o.x;
    #pragma unroll
    for (int kk = 0; kk < 4; ++kk) {
        const float* ck = &c[(k0 + kk) * CONE_STRIDE];
        const float vx = qx - ck[0];
        const float vy = qy - ck[1];
        const float vz = qz - ck[2];
        const float proj = vx*ck[3] + vy*ck[4] + vz*ck[5];
        const float d2 = vx*vx + vy*vy + vz*vz;
        float pp = d2 - proj * proj;
        pp = pp > 0.f ? pp : 0.f;
        const float perp = sqrtf(pp);
        const float slant = perp - ck[6] + ck[9] * proj;
        const float cap = fabsf(proj) - ck[7];
        of[kk] = slant > cap ? slant : cap;
    }
    *reinterpret_cast<float4*>(&out[(n0 + nl) * (size_t)KC + k0]) = o;
}

extern "C" void kernel_launch(void* const* d_in, const int* in_sizes, int n_in,
                              void* d_out, int out_size, void* d_ws, size_t ws_size,
                              hipStream_t stream) {
    const float* vox  = (const float*)d_in[0];
    const float* q    = (const float*)d_in[1];
    // d_in[2] = initial_centers: unused by the reference
    const float* Wenc = (const float*)d_in[3];
    const float* benc = (const float*)d_in[4];
    const float* Wdec = (const float*)d_in[5];
    const float* bdec = (const float*)d_in[6];
    const float* Wmap = (const float*)d_in[7];
    const float* bmap = (const float*)d_in[8];
    float* out = (float*)d_out;
    float* ws  = (float*)d_ws;

    unsigned int* cnt = (unsigned int*)ws;   // ws[0]
    float* cones      = ws + 16;             // 416 floats; read during k_sdf

    float* partialT = out + OFF_PART;
    float* decPart  = out + OFF_DECP;
    float* mapPart  = out + OFF_MAPP;
    float* out_params = out + (size_t)NQ * KC;

    k_enc<<<512, 512, 0, stream>>>(vox, Wenc, partialT, cnt);
    k_dec<<<128, 512, 0, stream>>>(partialT, benc, Wdec, decPart);
    k_map<<<64, 512, 0, stream>>>(decPart, bdec, Wmap, mapPart,
                                  bmap, out_params, cones, cnt);
    k_sdf<<<NQ / 32, 256, 0, stream>>>(q, cones, out);
}

// Round 4
// 48.460 us; speedup vs baseline: 1.1567x; 1.1567x over previous
//
#include <hip/hip_runtime.h>
#include <math.h>

#define DD 512
#define KC 32
#define NQ 524288
#define EPSF 1e-8f
#define CONE_STRIDE 13   // padded from 12 -> conflict-free LDS reads in k_sdf

__device__ __constant__ float c_mult[8]  = {1.f, 1.f, 1.f, 0.01f, 0.03f, 1.7f, 1.7f, 1.7f};
__device__ __constant__ float c_adder[8] = {-0.8f, -0.8f, -0.8f, 0.05f, 0.1f, -1.f, -1.f, -1.f};

// Stage 1: partialT[d][b] = sum over block b's 64 rows of vox[v]*W_enc[v][d].
// 512 blocks x 512 threads, coalesced float4 reads of W_enc (1KB/wave).
// 1MB transposed scatter store is absorbed by L2. No atomics anywhere.
__global__ __launch_bounds__(512) void k_enc(const float* __restrict__ vox,
                                             const float* __restrict__ Wenc,
                                             float* __restrict__ partialT) {
    __shared__ float4 red4[512];
    const int t = threadIdx.x;
    const int b = blockIdx.x;
    const int g  = t >> 7;          // row group 0..3
    const int c4 = (t & 127) << 2;  // starting column
    const int v0 = b * 64;
    float4 acc = make_float4(0.f, 0.f, 0.f, 0.f);
    #pragma unroll
    for (int it = 0; it < 16; ++it) {
        const int v = v0 + it * 4 + g;
        const float sv = vox[v];
        const float4 w = *reinterpret_cast<const float4*>(&Wenc[(size_t)v * DD + c4]);
        acc.x += sv * w.x; acc.y += sv * w.y; acc.z += sv * w.z; acc.w += sv * w.w;
    }
    red4[t] = acc;
    __syncthreads();
    const float* red = reinterpret_cast<const float*>(red4);
    const float s = red[t] + red[512 + t] + red[1024 + t] + red[1536 + t];
    partialT[(size_t)t * 512 + b] = s;
}

// Stage 2: decPart[b][d] = sum_{i in block b's 4 rows} relu(feat[i]+b_enc[i]) * W_dec[i][d]
// 128 blocks x 512 threads. feat row i reduced from partialT (coalesced float4
// + wave shuffle). Coalesced 2KB partial store. No atomics.
__global__ __launch_bounds__(512) void k_dec(const float* __restrict__ partialT,
                                             const float* __restrict__ benc,
                                             const float* __restrict__ Wdec,
                                             float* __restrict__ decPart) {
    __shared__ float4 red4[512];
    __shared__ float wsum[8];
    const int t = threadIdx.x;
    const int g = t >> 7;       // row group 0..3
    const int j = t & 127;
    const int i = blockIdx.x * 4 + g;
    const float4 pv = *reinterpret_cast<const float4*>(&partialT[(size_t)i * 512 + j * 4]);
    float s = pv.x + pv.y + pv.z + pv.w;
    #pragma unroll
    for (int off = 32; off >= 1; off >>= 1) s += __shfl_xor(s, off, 64);
    if ((t & 63) == 0) wsum[t >> 6] = s;
    __syncthreads();
    float fi = wsum[2 * g] + wsum[2 * g + 1] + benc[i];
    fi = fi > 0.f ? fi : 0.f;
    const float4 w = *reinterpret_cast<const float4*>(&Wdec[(size_t)i * DD + (j << 2)]);
    red4[t] = make_float4(fi * w.x, fi * w.y, fi * w.z, fi * w.w);
    __syncthreads();
    const float* red = reinterpret_cast<const float*>(red4);
    const float s2 = red[t] + red[512 + t] + red[1024 + t] + red[1536 + t];
    decPart[(size_t)blockIdx.x * 512 + t] = s2;   // coalesced, no atomics
}

// Stage 3: 64 blocks x 512 threads. Block b owns rows i = 8b..8b+7:
//   dec[i] = relu(sum_p decPart[p][i] + b_dec[i])   (one wave per row)
//   mapPart[b][j] = sum_r dec[8b+r] * W_map[8b+r][j]
// No atomics, no fences, no tail.
__global__ __launch_bounds__(512) void k_map(const float* __restrict__ decPart,
                                             const float* __restrict__ bdec,
                                             const float* __restrict__ Wmap,
                                             float* __restrict__ mapPart) {
    __shared__ float dec8[8];
    __shared__ float half0[256];
    const int t = threadIdx.x;
    const int b = blockIdx.x;
    const int w = t >> 6, l = t & 63;
    const int i = b * 8 + w;
    float s = decPart[(size_t)(2 * l) * 512 + i] + decPart[(size_t)(2 * l + 1) * 512 + i];
    #pragma unroll
    for (int off = 32; off >= 1; off >>= 1) s += __shfl_xor(s, off, 64);
    if (l == 0) {
        const float d = s + bdec[i];
        dec8[w] = d > 0.f ? d : 0.f;
    }
    __syncthreads();
    const int j = t & 255, h = t >> 8;
    float acc = 0.f;
    #pragma unroll
    for (int r = 0; r < 4; ++r) {
        const int row = h * 4 + r;
        acc += dec8[row] * Wmap[(size_t)(b * 8 + row) * 256 + j];
    }
    if (h == 0) half0[j] = acc;
    __syncthreads();
    if (h == 1) mapPart[(size_t)b * 256 + j] = half0[j] + acc;   // coalesced
}

// Stage 4: single block: reduce mapPart (64KB, L2-hot, coalesced), apply
// sigmoid*mult+adder, write the 256 output params + derived cone table.
__global__ __launch_bounds__(256) void k_params(const float* __restrict__ mapPart,
                                                const float* __restrict__ bmap,
                                                float* __restrict__ out_params,
                                                float* __restrict__ cones) {
    __shared__ float p[256];
    const int j = threadIdx.x;
    float m = 0.f;
    #pragma unroll 8
    for (int pi = 0; pi < 64; ++pi) m += mapPart[(size_t)pi * 256 + j];
    const float tot = m + bmap[j];
    const float sig = 1.f / (1.f + expf(-tot));
    const float val = sig * c_mult[j & 7] + c_adder[j & 7];
    out_params[j] = val;
    p[j] = val;
    __syncthreads();
    if (j < KC) {
        const float cx = p[j*8+0], cy = p[j*8+1], cz = p[j*8+2];
        const float r  = p[j*8+3], hh = p[j*8+4];
        const float ox = p[j*8+5], oy = p[j*8+6], oz = p[j*8+7];
        const float nrm = sqrtf(ox*ox + oy*oy + oz*oz) + EPSF;
        const float inv = 1.f / nrm;
        const float inv_h = 1.f / (hh + EPSF);
        float* ck = &cones[j * CONE_STRIDE];
        ck[0] = cx;        ck[1] = cy;       ck[2] = cz;
        ck[3] = ox * inv;  ck[4] = oy * inv; ck[5] = oz * inv;
        ck[6] = r;         ck[7] = hh;       ck[8] = inv_h;
        ck[9] = r * inv_h; ck[10] = 0.f;     ck[11] = 0.f;  ck[12] = 0.f;
    }
}

// Stage 5: SDF eval, fully coalesced 1KB/wave float4 writes.
// Block = 256 threads / 32 queries; thread t: query t>>3, cones (t&7)*4..+3.
__global__ __launch_bounds__(256) void k_sdf(const float* __restrict__ q,
                                             const float* __restrict__ cones,
                                             float* __restrict__ out) {
    __shared__ float sq[96];                 // 32 queries x 3
    __shared__ float c[KC * CONE_STRIDE];    // 416 floats
    const int t = threadIdx.x;
    const size_t n0 = (size_t)blockIdx.x * 32;
    if (t < 96) sq[t] = q[n0 * 3 + t];
    c[t] = cones[t];
    if (t < KC * CONE_STRIDE - 256) c[256 + t] = cones[256 + t];
    __syncthreads();
    const int nl = t >> 3;
    const int k0 = (t & 7) << 2;
    const float qx = sq[nl*3+0], qy = sq[nl*3+1], qz = sq[nl*3+2];
    float4 o;
    float* of = &o.x;
    #pragma unroll
    for (int kk = 0; kk < 4; ++kk) {
        const float* ck = &c[(k0 + kk) * CONE_STRIDE];
        const float vx = qx - ck[0];
        const float vy = qy - ck[1];
        const float vz = qz - ck[2];
        const float proj = vx*ck[3] + vy*ck[4] + vz*ck[5];
        const float d2 = vx*vx + vy*vy + vz*vz;
        float pp = d2 - proj * proj;
        pp = pp > 0.f ? pp : 0.f;
        const float perp = sqrtf(pp);
        const float slant = perp - ck[6] + ck[9] * proj;
        const float cap = fabsf(proj) - ck[7];
        of[kk] = slant > cap ? slant : cap;
    }
    *reinterpret_cast<float4*>(&out[(n0 + nl) * (size_t)KC + k0]) = o;
}

extern "C" void kernel_launch(void* const* d_in, const int* in_sizes, int n_in,
                              void* d_out, int out_size, void* d_ws, size_t ws_size,
                              hipStream_t stream) {
    const float* vox  = (const float*)d_in[0];
    const float* q    = (const float*)d_in[1];
    // d_in[2] = initial_centers: unused by the reference
    const float* Wenc = (const float*)d_in[3];
    const float* benc = (const float*)d_in[4];
    const float* Wdec = (const float*)d_in[5];
    const float* bdec = (const float*)d_in[6];
    const float* Wmap = (const float*)d_in[7];
    const float* bmap = (const float*)d_in[8];
    float* out = (float*)d_out;
    float* ws  = (float*)d_ws;

    // partialT (1MB) + cones always in ws (R2-proven size).
    float* partialT = ws;                        // [512][512]
    float *decPart, *mapPart, *cones;
    const size_t fullF = 262144 + 65536 + 16384 + 512;
    if (ws_size >= fullF * sizeof(float)) {
        decPart = ws + 262144;                   // [128][512]
        mapPart = decPart + 65536;               // [64][256]
        cones   = mapPart + 16384;
    } else {
        // spill partials to d_out's front: fully consumed by the next
        // dispatch, strictly before k_sdf overwrites them (stream order).
        decPart = out;                           // [128][512]
        mapPart = out + 65536;                   // [64][256]
        cones   = ws + 262144;                   // read DURING k_sdf -> ws
    }
    float* out_params = out + (size_t)NQ * KC;

    k_enc<<<512, 512, 0, stream>>>(vox, Wenc, partialT);
    k_dec<<<128, 512, 0, stream>>>(partialT, benc, Wdec, decPart);
    k_map<<<64, 512, 0, stream>>>(decPart, bdec, Wmap, mapPart);
    k_params<<<1, 256, 0, stream>>>(mapPart, bmap, out_params, cones);
    k_sdf<<<NQ / 32, 256, 0, stream>>>(q, cones, out);
}

// Round 5
// 45.638 us; speedup vs baseline: 1.2282x; 1.0618x over previous
//
#include <hip/hip_runtime.h>
#include <math.h>

#define DD 512
#define KC 32
#define NQ 524288
#define EPSF 1e-8f
#define CONE_STRIDE 13   // padded from 12 -> conflict-free LDS reads in k_sdf

typedef float f4 __attribute__((ext_vector_type(4)));

__device__ __constant__ float c_mult[8]  = {1.f, 1.f, 1.f, 0.01f, 0.03f, 1.7f, 1.7f, 1.7f};
__device__ __constant__ float c_adder[8] = {-0.8f, -0.8f, -0.8f, 0.05f, 0.1f, -1.f, -1.f, -1.f};

// Stage 1: partialT[d][b] = sum over block b's 64 rows of vox[v]*W_enc[v][d].
// 512 blocks x 512 threads, coalesced float4 reads of W_enc (1KB/wave).
__global__ __launch_bounds__(512) void k_enc(const float* __restrict__ vox,
                                             const float* __restrict__ Wenc,
                                             float* __restrict__ partialT) {
    __shared__ float4 red4[512];
    const int t = threadIdx.x;
    const int b = blockIdx.x;
    const int g  = t >> 7;          // row group 0..3
    const int c4 = (t & 127) << 2;  // starting column
    const int v0 = b * 64;
    float4 acc = make_float4(0.f, 0.f, 0.f, 0.f);
    #pragma unroll
    for (int it = 0; it < 16; ++it) {
        const int v = v0 + it * 4 + g;
        const float sv = vox[v];
        const float4 w = *reinterpret_cast<const float4*>(&Wenc[(size_t)v * DD + c4]);
        acc.x += sv * w.x; acc.y += sv * w.y; acc.z += sv * w.z; acc.w += sv * w.w;
    }
    red4[t] = acc;
    __syncthreads();
    const float* red = reinterpret_cast<const float*>(red4);
    const float s = red[t] + red[512 + t] + red[1024 + t] + red[1536 + t];
    partialT[(size_t)t * 512 + b] = s;
}

// Stage 2: decPart[b][d] = sum_{i in block b's 4 rows} relu(feat[i]+b_enc[i]) * W_dec[i][d]
__global__ __launch_bounds__(512) void k_dec(const float* __restrict__ partialT,
                                             const float* __restrict__ benc,
                                             const float* __restrict__ Wdec,
                                             float* __restrict__ decPart) {
    __shared__ float4 red4[512];
    __shared__ float wsum[8];
    const int t = threadIdx.x;
    const int g = t >> 7;       // row group 0..3
    const int j = t & 127;
    const int i = blockIdx.x * 4 + g;
    const float4 pv = *reinterpret_cast<const float4*>(&partialT[(size_t)i * 512 + j * 4]);
    float s = pv.x + pv.y + pv.z + pv.w;
    #pragma unroll
    for (int off = 32; off >= 1; off >>= 1) s += __shfl_xor(s, off, 64);
    if ((t & 63) == 0) wsum[t >> 6] = s;
    __syncthreads();
    float fi = wsum[2 * g] + wsum[2 * g + 1] + benc[i];
    fi = fi > 0.f ? fi : 0.f;
    const float4 w = *reinterpret_cast<const float4*>(&Wdec[(size_t)i * DD + (j << 2)]);
    red4[t] = make_float4(fi * w.x, fi * w.y, fi * w.z, fi * w.w);
    __syncthreads();
    const float* red = reinterpret_cast<const float*>(red4);
    const float s2 = red[t] + red[512 + t] + red[1024 + t] + red[1536 + t];
    decPart[(size_t)blockIdx.x * 512 + t] = s2;   // coalesced, no atomics
}

// Stage 3: block b owns rows i = 8b..8b+7 -> mapPart[b][j].
__global__ __launch_bounds__(512) void k_map(const float* __restrict__ decPart,
                                             const float* __restrict__ bdec,
                                             const float* __restrict__ Wmap,
                                             float* __restrict__ mapPart) {
    __shared__ float dec8[8];
    __shared__ float half0[256];
    const int t = threadIdx.x;
    const int b = blockIdx.x;
    const int w = t >> 6, l = t & 63;
    const int i = b * 8 + w;
    float s = decPart[(size_t)(2 * l) * 512 + i] + decPart[(size_t)(2 * l + 1) * 512 + i];
    #pragma unroll
    for (int off = 32; off >= 1; off >>= 1) s += __shfl_xor(s, off, 64);
    if (l == 0) {
        const float d = s + bdec[i];
        dec8[w] = d > 0.f ? d : 0.f;
    }
    __syncthreads();
    const int j = t & 255, h = t >> 8;
    float acc = 0.f;
    #pragma unroll
    for (int r = 0; r < 4; ++r) {
        const int row = h * 4 + r;
        acc += dec8[row] * Wmap[(size_t)(b * 8 + row) * 256 + j];
    }
    if (h == 0) half0[j] = acc;
    __syncthreads();
    if (h == 1) mapPart[(size_t)b * 256 + j] = half0[j] + acc;   // coalesced
}

// Stage 4: single block: reduce mapPart, sigmoid*mult+adder, params + cones.
__global__ __launch_bounds__(256) void k_params(const float* __restrict__ mapPart,
                                                const float* __restrict__ bmap,
                                                float* __restrict__ out_params,
                                                float* __restrict__ cones) {
    __shared__ float p[256];
    const int j = threadIdx.x;
    float m = 0.f;
    #pragma unroll 8
    for (int pi = 0; pi < 64; ++pi) m += mapPart[(size_t)pi * 256 + j];
    const float tot = m + bmap[j];
    const float sig = 1.f / (1.f + expf(-tot));
    const float val = sig * c_mult[j & 7] + c_adder[j & 7];
    out_params[j] = val;
    p[j] = val;
    __syncthreads();
    if (j < KC) {
        const float cx = p[j*8+0], cy = p[j*8+1], cz = p[j*8+2];
        const float r  = p[j*8+3], hh = p[j*8+4];
        const float ox = p[j*8+5], oy = p[j*8+6], oz = p[j*8+7];
        const float nrm = sqrtf(ox*ox + oy*oy + oz*oz) + EPSF;
        const float inv = 1.f / nrm;
        const float inv_h = 1.f / (hh + EPSF);
        float* ck = &cones[j * CONE_STRIDE];
        ck[0] = cx;        ck[1] = cy;       ck[2] = cz;
        ck[3] = ox * inv;  ck[4] = oy * inv; ck[5] = oz * inv;
        ck[6] = r;         ck[7] = hh;       ck[8] = inv_h;
        ck[9] = r * inv_h; ck[10] = 0.f;     ck[11] = 0.f;  ck[12] = 0.f;
    }
}

// Stage 5: SDF eval — fat persistent-style blocks.
// grid = 2048 blocks x 256 threads (8 blocks/CU, 32 waves/CU).
// Block b owns 256 contiguous queries (8 tiles of 32). Thread t: within each
// tile, query (t>>3), cones (t&7)*4..+3. Cone params hoisted to registers
// once; loop body = 3 query loads + VALU + 1 nontemporal float4 store.
__global__ __launch_bounds__(256) void k_sdf(const float* __restrict__ q,
                                             const float* __restrict__ cones,
                                             float* __restrict__ out) {
    __shared__ float c[KC * CONE_STRIDE];    // 416 floats
    const int t = threadIdx.x;
    c[t] = cones[t];
    if (t < KC * CONE_STRIDE - 256) c[256 + t] = cones[256 + t];
    __syncthreads();
    const int k0 = (t & 7) << 2;
    // hoist 4 cones x 9 params into registers
    float cx[4], cy[4], cz[4], ax[4], ay[4], az[4], cr[4], chh[4], rih[4];
    #pragma unroll
    for (int kk = 0; kk < 4; ++kk) {
        const float* ck = &c[(k0 + kk) * CONE_STRIDE];
        cx[kk] = ck[0]; cy[kk] = ck[1]; cz[kk] = ck[2];
        ax[kk] = ck[3]; ay[kk] = ck[4]; az[kk] = ck[5];
        cr[kk] = ck[6]; chh[kk] = ck[7]; rih[kk] = ck[9];
    }
    const size_t qbase = (size_t)blockIdx.x * 256;
    const int nl = t >> 3;
    #pragma unroll
    for (int tile = 0; tile < 8; ++tile) {
        const size_t n = qbase + tile * 32 + nl;
        const float qx = q[n * 3 + 0];
        const float qy = q[n * 3 + 1];
        const float qz = q[n * 3 + 2];
        f4 o;
        #pragma unroll
        for (int kk = 0; kk < 4; ++kk) {
            const float vx = qx - cx[kk];
            const float vy = qy - cy[kk];
            const float vz = qz - cz[kk];
            const float proj = vx*ax[kk] + vy*ay[kk] + vz*az[kk];
            const float d2 = vx*vx + vy*vy + vz*vz;
            float pp = d2 - proj * proj;
            pp = pp > 0.f ? pp : 0.f;
            const float perp = sqrtf(pp);
            const float slant = perp - cr[kk] + rih[kk] * proj;
            const float cap = fabsf(proj) - chh[kk];
            o[kk] = slant > cap ? slant : cap;
        }
        __builtin_nontemporal_store(o, reinterpret_cast<f4*>(&out[n * (size_t)KC + k0]));
    }
}

extern "C" void kernel_launch(void* const* d_in, const int* in_sizes, int n_in,
                              void* d_out, int out_size, void* d_ws, size_t ws_size,
                              hipStream_t stream) {
    const float* vox  = (const float*)d_in[0];
    const float* q    = (const float*)d_in[1];
    // d_in[2] = initial_centers: unused by the reference
    const float* Wenc = (const float*)d_in[3];
    const float* benc = (const float*)d_in[4];
    const float* Wdec = (const float*)d_in[5];
    const float* bdec = (const float*)d_in[6];
    const float* Wmap = (const float*)d_in[7];
    const float* bmap = (const float*)d_in[8];
    float* out = (float*)d_out;
    float* ws  = (float*)d_ws;

    float* partialT = ws;                        // [512][512]
    float *decPart, *mapPart, *cones;
    const size_t fullF = 262144 + 65536 + 16384 + 512;
    if (ws_size >= fullF * sizeof(float)) {
        decPart = ws + 262144;                   // [128][512]
        mapPart = decPart + 65536;               // [64][256]
        cones   = mapPart + 16384;
    } else {
        // spill partials to d_out's front: fully consumed by the next
        // dispatch, strictly before k_sdf overwrites them (stream order).
        decPart = out;                           // [128][512]
        mapPart = out + 65536;                   // [64][256]
        cones   = ws + 262144;                   // read DURING k_sdf -> ws
    }
    float* out_params = out + (size_t)NQ * KC;

    k_enc<<<512, 512, 0, stream>>>(vox, Wenc, partialT);
    k_dec<<<128, 512, 0, stream>>>(partialT, benc, Wdec, decPart);
    k_map<<<64, 512, 0, stream>>>(decPart, bdec, Wmap, mapPart);
    k_params<<<1, 256, 0, stream>>>(mapPart, bmap, out_params, cones);
    k_sdf<<<2048, 256, 0, stream>>>(q, cones, out);
}